// Round 1
// baseline (897.832 us; speedup 1.0000x reference)
//
#include <hip/hip_runtime.h>
#include <hip/hip_bf16.h>
#include <math.h>

#define HD 2048
#define ID 1024
#define NE 32
#define TOPK 4
#define NTOK 4096
#define NSLOT (NTOK*TOPK)

typedef __attribute__((ext_vector_type(4))) float f32x4;
typedef __attribute__((ext_vector_type(8))) short bf16x8;
typedef unsigned short u16;
typedef unsigned int u32;

static __device__ __forceinline__ u16 f2bf(float f) {
  union { float f; u32 u; } v; v.f = f;
  u32 r = v.u + 0x7fffu + ((v.u >> 16) & 1u);
  return (u16)(r >> 16);
}

// ---------------- RMSNorm -> bf16 ----------------
__global__ __launch_bounds__(256) void k_rmsnorm(const float* __restrict__ x,
                                                 const float* __restrict__ w,
                                                 u16* __restrict__ xn) {
  int t = blockIdx.x, tid = threadIdx.x;
  const float* row = x + (size_t)t * HD;
  float4 v0 = ((const float4*)row)[tid*2+0];
  float4 v1 = ((const float4*)row)[tid*2+1];
  float ss = v0.x*v0.x+v0.y*v0.y+v0.z*v0.z+v0.w*v0.w
           + v1.x*v1.x+v1.y*v1.y+v1.z*v1.z+v1.w*v1.w;
  #pragma unroll
  for (int d=1; d<64; d<<=1) ss += __shfl_xor(ss, d);
  __shared__ float red[4];
  if ((tid&63)==0) red[tid>>6] = ss;
  __syncthreads();
  float rs = rsqrtf((red[0]+red[1]+red[2]+red[3]) * (1.0f/HD) + 1e-6f);
  const float* wp = w + tid*8;
  float a[8] = {v0.x,v0.y,v0.z,v0.w,v1.x,v1.y,v1.z,v1.w};
  uint4 o;
  o.x = (u32)f2bf(a[0]*rs*wp[0]) | ((u32)f2bf(a[1]*rs*wp[1])<<16);
  o.y = (u32)f2bf(a[2]*rs*wp[2]) | ((u32)f2bf(a[3]*rs*wp[3])<<16);
  o.z = (u32)f2bf(a[4]*rs*wp[4]) | ((u32)f2bf(a[5]*rs*wp[5])<<16);
  o.w = (u32)f2bf(a[6]*rs*wp[6]) | ((u32)f2bf(a[7]*rs*wp[7])<<16);
  ((uint4*)xn)[(size_t)t*(HD/8) + tid] = o;
}

// ---------------- Gate: logits fp32, top-4, weights, counts ----------------
__global__ __launch_bounds__(256) void k_gate(const float* __restrict__ x,
                                              const float* __restrict__ w,
                                              const float* __restrict__ gw,
                                              int* __restrict__ topk_id,
                                              float* __restrict__ topk_w,
                                              int* __restrict__ counts) {
  __shared__ float xs[HD];
  __shared__ float red[4];
  __shared__ float logits[NE];
  int t = blockIdx.x, tid = threadIdx.x;
  const float* row = x + (size_t)t*HD;
  float4 v0 = ((const float4*)row)[tid*2+0];
  float4 v1 = ((const float4*)row)[tid*2+1];
  float ss = v0.x*v0.x+v0.y*v0.y+v0.z*v0.z+v0.w*v0.w
           + v1.x*v1.x+v1.y*v1.y+v1.z*v1.z+v1.w*v1.w;
  #pragma unroll
  for (int d=1; d<64; d<<=1) ss += __shfl_xor(ss, d);
  if ((tid&63)==0) red[tid>>6] = ss;
  __syncthreads();
  float rs = 1.0f / sqrtf((red[0]+red[1]+red[2]+red[3]) * (1.0f/HD) + 1e-6f);
  const float* wp = w + tid*8;
  float a[8] = {v0.x,v0.y,v0.z,v0.w,v1.x,v1.y,v1.z,v1.w};
  #pragma unroll
  for (int j=0;j<8;++j) xs[tid*8+j] = a[j]*rs*wp[j];
  __syncthreads();
  int wave = tid>>6, lane = tid&63;
  for (int ei=0; ei<8; ++ei) {
    int e = wave*8 + ei;
    const float* g = gw + (size_t)e*HD;
    float s = 0.f;
    #pragma unroll
    for (int j=0;j<HD/64;++j) s += xs[lane + j*64] * g[lane + j*64];
    #pragma unroll
    for (int d=1; d<64; d<<=1) s += __shfl_xor(s, d);
    if (lane==0) logits[e] = s;
  }
  __syncthreads();
  if (tid==0) {
    float best[TOPK]; int bid[TOPK]; unsigned used = 0;
    for (int k2=0;k2<TOPK;++k2) {
      float bv = -1e30f; int bi = 0;
      for (int i2=0;i2<NE;++i2)
        if (!((used>>i2)&1u) && logits[i2] > bv) { bv = logits[i2]; bi = i2; }
      used |= 1u<<bi; best[k2] = bv; bid[k2] = bi;
    }
    float mx = best[0], sum = 0.f, wv[TOPK];
    for (int k2=0;k2<TOPK;++k2) { wv[k2] = expf(best[k2]-mx); sum += wv[k2]; }
    float inv = 1.f/sum;
    for (int k2=0;k2<TOPK;++k2) {
      topk_id[t*TOPK+k2] = bid[k2];
      topk_w[t*TOPK+k2] = wv[k2]*inv;
      atomicAdd(&counts[bid[k2]], 1);
    }
  }
}

__global__ void k_zero(int* counts, int* cursors) {
  int i = threadIdx.x;
  if (i < NE) { counts[i] = 0; cursors[i] = 0; }
}

__global__ void k_scan(const int* __restrict__ counts, int* __restrict__ starts) {
  if (threadIdx.x==0 && blockIdx.x==0) {
    int acc = 0;
    for (int e=0;e<NE;++e) { starts[e] = acc; acc += counts[e]; }
  }
}

__global__ __launch_bounds__(256) void k_dispatch(const int* __restrict__ topk_id,
                                                  const float* __restrict__ topk_w,
                                                  const int* __restrict__ starts,
                                                  int* __restrict__ cursors,
                                                  int* __restrict__ slot_tok,
                                                  float* __restrict__ slot_w) {
  int i = blockIdx.x*256 + threadIdx.x;
  int e = topk_id[i];
  int p = atomicAdd(&cursors[e], 1);
  int slot = starts[e] + p;
  slot_tok[slot] = i >> 2;   // token = pair/TOPK
  slot_w[slot] = topk_w[i];
}

// ---------------- GEMM up (x @ [Wg|Wu]) + SwiGLU -> act bf16 ----------------
// tile: BM=128 rows x 64 gate cols + 64 up cols (interleaved 16-col blocks in LDS)
template<bool INDEXED>
__global__ __launch_bounds__(256) void k_gemm_up(
    const u16* __restrict__ A,             // xn bf16 [*, HD]
    const float* __restrict__ Bg, const float* __restrict__ Bu,
    size_t bstride, int ldb,
    const int* __restrict__ counts, const int* __restrict__ starts,
    const int* __restrict__ slot_tok,
    u16* __restrict__ actOut) {
  __shared__ u16 Al[128*32];
  __shared__ u16 Bl[128*32];
  __shared__ int rowL[128];
  int tid = threadIdx.x;
  int n0 = blockIdx.x * 64;
  int m0 = blockIdx.y * 128;
  int e  = blockIdx.z;
  int M, rowbase;
  if (INDEXED) { M = counts[e]; rowbase = starts[e]; if (m0 >= M) return; }
  else { M = NTOK; rowbase = 0; }
  if (tid < 128) {
    int m = m0 + tid;
    if (INDEXED) rowL[tid] = slot_tok[rowbase + (m < M ? m : M-1)];
    else rowL[tid] = m;
  }
  __syncthreads();
  // A staging: 2 slots per thread, slot s -> (row s>>2, phys seg s&3), logical seg = phys ^ ((s>>3)&3)
  int s0 = tid, s1 = tid + 256;
  int segl0 = (s0&3) ^ ((s0>>3)&3);
  const u16* srcA0 = A + (size_t)rowL[s0>>2]*HD + (segl0<<3);
  const u16* srcA1 = A + (size_t)rowL[s1>>2]*HD + (segl0<<3);
  // B staging: thread covers cols c4..c4+3, k rows kb..kb+3
  int c4 = (tid&31)*4, kb = (tid>>5)*4;
  int isup = (c4>>4)&1, pgrp = c4>>5;
  const float* bp = (isup ? Bu : Bg) + (size_t)e*bstride + (n0 + pgrp*16 + (c4&15));
  int bwid[4];
  #pragma unroll
  for (int i=0;i<4;++i)
    bwid[i] = (c4+i)*32 + (((kb>>3) ^ (tid&3))<<3) + (((kb>>2)&1)<<2);
  // wave / frag offsets
  int lane = tid&63, wave = tid>>6;
  int wr = wave>>1, wc = wave&1;
  int l15 = lane&15, l4 = lane>>4;
  int aoff[4], boff[4];
  #pragma unroll
  for (int f=0; f<4; ++f) {
    int r = wr*64 + f*16 + l15;
    aoff[f] = r*32 + ((l4 ^ ((l15>>1)&3))<<3);
    int c = wc*64 + f*16 + l15;
    boff[f] = c*32 + ((l4 ^ ((l15>>2)&3))<<3);
  }
  f32x4 acc[4][4];
  #pragma unroll
  for (int fm=0;fm<4;++fm)
    #pragma unroll
    for (int fn=0;fn<4;++fn)
      acc[fm][fn] = (f32x4){0.f,0.f,0.f,0.f};

  const int KSTEPS = HD/32;
  for (int kt=0; kt<KSTEPS; ++kt) {
    int k0 = kt*32;
    uint4 av0 = *(const uint4*)(srcA0 + k0);
    uint4 av1 = *(const uint4*)(srcA1 + k0);
    float4 Lb[4];
    #pragma unroll
    for (int j=0;j<4;++j) Lb[j] = *(const float4*)(bp + (size_t)(k0+kb+j)*ldb);
    __syncthreads();
    *(uint4*)&Al[s0*8] = av0;
    *(uint4*)&Al[s1*8] = av1;
    #pragma unroll
    for (int i=0;i<4;++i) {
      uint2 wv;
      wv.x = (u32)f2bf(((const float*)&Lb[0])[i]) | ((u32)f2bf(((const float*)&Lb[1])[i])<<16);
      wv.y = (u32)f2bf(((const float*)&Lb[2])[i]) | ((u32)f2bf(((const float*)&Lb[3])[i])<<16);
      *(uint2*)&Bl[bwid[i]] = wv;
    }
    __syncthreads();
    bf16x8 af[4], bfr[4];
    #pragma unroll
    for (int f=0; f<4; ++f) af[f] = *(const bf16x8*)&Al[aoff[f]];
    #pragma unroll
    for (int f=0; f<4; ++f) bfr[f] = *(const bf16x8*)&Bl[boff[f]];
    #pragma unroll
    for (int fm=0; fm<4; ++fm)
      #pragma unroll
      for (int fn=0; fn<4; ++fn)
        acc[fm][fn] = __builtin_amdgcn_mfma_f32_16x16x32_bf16(af[fm], bfr[fn], acc[fm][fn], 0,0,0);
  }
  // epilogue: SwiGLU on (gate,up) fragment pairs
  #pragma unroll
  for (int fm=0; fm<4; ++fm) {
    #pragma unroll
    for (int fq=0; fq<2; ++fq) {
      f32x4 g = acc[fm][2*fq], u = acc[fm][2*fq+1];
      int col = n0 + (wc*2+fq)*16 + l15;
      #pragma unroll
      for (int r=0;r<4;++r) {
        int mloc = wr*64 + fm*16 + l4*4 + r;
        int m = m0 + mloc;
        if (m < M) {
          float gv = g[r];
          float av = gv / (1.f + expf(-gv)) * u[r];
          actOut[(size_t)(rowbase+m)*ID + col] = f2bf(av);
        }
      }
    }
  }
}

// ---------------- GEMM down (act @ W2) ----------------
template<bool INDEXED>
__global__ __launch_bounds__(256) void k_gemm_down(
    const u16* __restrict__ A,             // act/sact bf16 [*, ID]
    const float* __restrict__ B,
    size_t bstride, int ldb,
    const int* __restrict__ counts, const int* __restrict__ starts,
    const int* __restrict__ slot_tok, const float* __restrict__ slot_w,
    const float* __restrict__ resid,
    float* __restrict__ out) {
  __shared__ u16 Al[128*32];
  __shared__ u16 Bl[128*32];
  __shared__ int rowL[128];
  __shared__ int tokL[128];
  __shared__ float wL[128];
  int tid = threadIdx.x;
  int n0 = blockIdx.x * 128;
  int m0 = blockIdx.y * 128;
  int e  = blockIdx.z;
  int M, rowbase;
  if (INDEXED) { M = counts[e]; rowbase = starts[e]; if (m0 >= M) return; }
  else { M = NTOK; rowbase = 0; }
  if (tid < 128) {
    int m = m0 + tid;
    int cm = m < M ? m : M-1;
    rowL[tid] = rowbase + cm;
    if (INDEXED) {
      tokL[tid] = (m<M) ? slot_tok[rowbase+m] : 0;
      wL[tid]   = (m<M) ? slot_w[rowbase+m]  : 0.f;
    }
  }
  __syncthreads();
  int s0 = tid, s1 = tid + 256;
  int segl0 = (s0&3) ^ ((s0>>3)&3);
  const u16* srcA0 = A + (size_t)rowL[s0>>2]*ID + (segl0<<3);
  const u16* srcA1 = A + (size_t)rowL[s1>>2]*ID + (segl0<<3);
  int c4 = (tid&31)*4, kb = (tid>>5)*4;
  const float* bp = B + (size_t)e*bstride + n0 + c4;
  int bwid[4];
  #pragma unroll
  for (int i=0;i<4;++i)
    bwid[i] = (c4+i)*32 + (((kb>>3) ^ (tid&3))<<3) + (((kb>>2)&1)<<2);
  int lane = tid&63, wave = tid>>6;
  int wr = wave>>1, wc = wave&1;
  int l15 = lane&15, l4 = lane>>4;
  int aoff[4], boff[4];
  #pragma unroll
  for (int f=0; f<4; ++f) {
    int r = wr*64 + f*16 + l15;
    aoff[f] = r*32 + ((l4 ^ ((l15>>1)&3))<<3);
    int c = wc*64 + f*16 + l15;
    boff[f] = c*32 + ((l4 ^ ((l15>>2)&3))<<3);
  }
  f32x4 acc[4][4];
  #pragma unroll
  for (int fm=0;fm<4;++fm)
    #pragma unroll
    for (int fn=0;fn<4;++fn)
      acc[fm][fn] = (f32x4){0.f,0.f,0.f,0.f};

  const int KSTEPS = ID/32;
  for (int kt=0; kt<KSTEPS; ++kt) {
    int k0 = kt*32;
    uint4 av0 = *(const uint4*)(srcA0 + k0);
    uint4 av1 = *(const uint4*)(srcA1 + k0);
    float4 Lb[4];
    #pragma unroll
    for (int j=0;j<4;++j) Lb[j] = *(const float4*)(bp + (size_t)(k0+kb+j)*ldb);
    __syncthreads();
    *(uint4*)&Al[s0*8] = av0;
    *(uint4*)&Al[s1*8] = av1;
    #pragma unroll
    for (int i=0;i<4;++i) {
      uint2 wv;
      wv.x = (u32)f2bf(((const float*)&Lb[0])[i]) | ((u32)f2bf(((const float*)&Lb[1])[i])<<16);
      wv.y = (u32)f2bf(((const float*)&Lb[2])[i]) | ((u32)f2bf(((const float*)&Lb[3])[i])<<16);
      *(uint2*)&Bl[bwid[i]] = wv;
    }
    __syncthreads();
    bf16x8 af[4], bfr[4];
    #pragma unroll
    for (int f=0; f<4; ++f) af[f] = *(const bf16x8*)&Al[aoff[f]];
    #pragma unroll
    for (int f=0; f<4; ++f) bfr[f] = *(const bf16x8*)&Bl[boff[f]];
    #pragma unroll
    for (int fm=0; fm<4; ++fm)
      #pragma unroll
      for (int fn=0; fn<4; ++fn)
        acc[fm][fn] = __builtin_amdgcn_mfma_f32_16x16x32_bf16(af[fm], bfr[fn], acc[fm][fn], 0,0,0);
  }
  #pragma unroll
  for (int fm=0; fm<4; ++fm) {
    #pragma unroll
    for (int fn=0; fn<4; ++fn) {
      f32x4 v = acc[fm][fn];
      int col = n0 + wc*64 + fn*16 + l15;
      #pragma unroll
      for (int r=0;r<4;++r) {
        int mloc = wr*64 + fm*16 + l4*4 + r;
        int m = m0 + mloc;
        if (m < M) {
          if (INDEXED) {
            atomicAdd(&out[(size_t)tokL[mloc]*HD + col], v[r]*wL[mloc]);
          } else {
            size_t o = (size_t)m*HD + col;
            out[o] = resid[o] + v[r];
          }
        }
      }
    }
  }
}

extern "C" void kernel_launch(void* const* d_in, const int* in_sizes, int n_in,
                              void* d_out, int out_size, void* d_ws, size_t ws_size,
                              hipStream_t stream) {
  const float* x    = (const float*)d_in[0];
  const float* nw   = (const float*)d_in[1];
  const float* gw   = (const float*)d_in[2];
  const float* w13  = (const float*)d_in[3];
  const float* w2   = (const float*)d_in[4];
  const float* sgw  = (const float*)d_in[5];
  const float* suw  = (const float*)d_in[6];
  const float* sdw  = (const float*)d_in[7];
  float* out = (float*)d_out;

  char* p = (char*)d_ws;
  u16* xn   = (u16*)p;    p += (size_t)NTOK*HD*2;
  u16* act  = (u16*)p;    p += (size_t)NSLOT*ID*2;
  u16* sact = (u16*)p;    p += (size_t)NTOK*ID*2;
  int*   topk_id  = (int*)p;   p += (size_t)NTOK*TOPK*4;
  float* topk_w   = (float*)p; p += (size_t)NTOK*TOPK*4;
  int*   slot_tok = (int*)p;   p += (size_t)NSLOT*4;
  float* slot_w   = (float*)p; p += (size_t)NSLOT*4;
  int*   counts   = (int*)p;   p += 64*4;
  int*   cursors  = (int*)p;   p += 64*4;
  int*   starts   = (int*)p;   p += 64*4;

  k_zero<<<1, 64, 0, stream>>>(counts, cursors);
  k_rmsnorm<<<NTOK, 256, 0, stream>>>(x, nw, xn);
  k_gate<<<NTOK, 256, 0, stream>>>(x, nw, gw, topk_id, topk_w, counts);
  k_scan<<<1, 1, 0, stream>>>(counts, starts);
  k_dispatch<<<NSLOT/256, 256, 0, stream>>>(topk_id, topk_w, starts, cursors, slot_tok, slot_w);

  // routed up-proj + swiglu: grid (n-tiles of 64 act cols, m-tiles(cap 1024), experts)
  k_gemm_up<true><<<dim3(ID/64, 8, NE), 256, 0, stream>>>(
      xn, w13, w13 + ID, (size_t)HD*2*ID, 2*ID, counts, starts, slot_tok, act);
  // shared up-proj + swiglu
  k_gemm_up<false><<<dim3(ID/64, NTOK/128, 1), 256, 0, stream>>>(
      xn, sgw, suw, (size_t)0, ID, nullptr, nullptr, nullptr, sact);
  // shared down-proj: out = residual + shared
  k_gemm_down<false><<<dim3(HD/128, NTOK/128, 1), 256, 0, stream>>>(
      sact, sdw, (size_t)0, HD, nullptr, nullptr, nullptr, nullptr, x, out);
  // routed down-proj: atomic weighted scatter-add into out
  k_gemm_down<true><<<dim3(HD/128, 8, NE), 256, 0, stream>>>(
      act, w2, (size_t)ID*HD, HD, counts, starts, slot_tok, slot_w, nullptr, out);
}